// Round 5
// baseline (265.196 us; speedup 1.0000x reference)
//
#include <hip/hip_runtime.h>

#define MAXB 64
#define CAP 256

__constant__ float c_anc[9][2] = {
    {116.f, 90.f}, {156.f, 198.f}, {373.f, 326.f},
    { 30.f, 61.f}, { 62.f, 45.f}, { 59.f, 119.f},
    { 10.f, 13.f}, { 16.f, 30.f}, { 33.f, 23.f}};

typedef float floatx4 __attribute__((ext_vector_type(4), aligned(4)));

// fast transcendentals (v_exp/v_log/v_rcp); ~1e-6 rel per term, output ~1.7e4
// with threshold 345.6 -> ample margin.
__device__ __forceinline__ float sigm(float x) {
    return __builtin_amdgcn_rcpf(1.f + __expf(-x));
}
// bce_logits(t,x) = max(x,0) - x*t + log1p(exp(-|x|))
__device__ __forceinline__ float bce_f(float t, float x) {
    return fmaxf(x, 0.f) - x * t + __logf(1.f + __expf(-fabsf(x)));
}

// block j (0..41 within a batch) -> layer l, chunk blk, grid S, offsets
__device__ __forceinline__ void map_block(int j, int& l, int& blk, int& S,
                                          int& n0, int& nwords) {
    if (j < 2)       { l = 0; blk = j;      S = 13; n0 = 0;   nwords = 8;   }
    else if (j < 10) { l = 1; blk = j - 2;  S = 26; n0 = 169; nwords = 32;  }
    else             { l = 2; blk = j - 10; S = 52; n0 = 845; nwords = 128; }
}

// wave wv scans words wv, wv+4, ... ; all loads issued up-front
template <int ITERS>
__device__ __forceinline__ void scan_obj(const float* __restrict__ ybase,
                                         int nCells, int lane, int wv,
                                         unsigned long long* swords) {
    float ov[ITERS];
#pragma unroll
    for (int k = 0; k < ITERS; ++k) {
        int c = (((k << 2) + wv) << 6) + lane;
        ov[k] = (c < nCells) ? ybase[(long long)c * 85] : 0.f;
    }
#pragma unroll
    for (int k = 0; k < ITERS; ++k) {
        unsigned long long m = __ballot(ov[k] > 0.5f);
        if (lane == 0) swords[(k << 2) + wv] = m;
    }
}

__global__ void init_k(float* __restrict__ out) { out[threadIdx.x] = 0.f; }

// Fully self-contained: each block derives the positive set of its
// (batch,layer) pair from y_true directly (no workspace round-trip).
__global__ __launch_bounds__(256) void loss_k(
    const float* __restrict__ yt,
    const float* __restrict__ p13, const float* __restrict__ p26,
    const float* __restrict__ p52, float* __restrict__ out)
{
    int bid = blockIdx.x, tid = threadIdx.x;
    int b = bid / 42, j = bid - b * 42;
    int l, blk, S, n0, nwords;
    map_block(j, l, blk, S, n0, nwords);
    int nCells = S * S * 3;
    float Sf = (float)S;
    float invS = __builtin_amdgcn_rcpf(Sf);
    const float* ybase = yt + (long long)(b * 3549 + n0) * 255;
    const float* pred  = (l == 0) ? p13 : (l == 1) ? p26 : p52;
    const float* pbase = pred + (long long)b * S * S * 255;
    int lane = tid & 63, wv = tid >> 6;

    // issue this chunk's pred loads immediately (independent of LDS work)
    int c = blk * 256 + tid;
    bool act = c < nCells;
    int cc = act ? c : 0;
    const float* pcp = pbase + (long long)cc * 85;
    floatx4 v03 = *(const floatx4*)pcp;
    float v4 = pcp[4];

    __shared__ unsigned long long swords[128];
    __shared__ int sidx[CAP];
    __shared__ int sbase2[2];
    __shared__ int stot_s;
    __shared__ float sxmin[MAXB], sxmax[MAXB], symin[MAXB], symax[MAXB], sba[MAXB];

    if (l == 0)      scan_obj<2 >(ybase, nCells, lane, wv, swords);
    else if (l == 1) scan_obj<8 >(ybase, nCells, lane, wv, swords);
    else             scan_obj<32>(ybase, nCells, lane, wv, swords);
    __syncthreads();

    // exclusive prefix over word popcounts (log-step shfl scan, waves 0/1)
    unsigned long long w = 0ULL;
    int pc = 0;
    if (tid < 128) { w = (tid < nwords) ? swords[tid] : 0ULL; pc = __popcll(w); }
    int x = pc;
#pragma unroll
    for (int d = 1; d < 64; d <<= 1) {
        int y = __shfl_up(x, d, 64);
        if (lane >= d) x += y;
    }
    if (tid < 128 && lane == 63) sbase2[wv] = x;
    __syncthreads();
    if (tid == 0) stot_s = sbase2[0] + sbase2[1];
    if (tid < 128) {
        int base = x - pc + (wv ? sbase2[0] : 0);
        unsigned long long ww = w;
        while (ww) {
            int bit = __ffsll((long long)ww) - 1;
            if (base < CAP) sidx[base] = tid * 64 + bit;
            ++base;
            ww &= ww - 1;
        }
    }
    __syncthreads();

    int stot = stot_s;
    int TC = stot < CAP ? stot : CAP;
    int MB = TC < MAXB ? TC : MAXB;   // == top_k(64) box set (index-ordered)
    if (tid < MB) {
        int idx = sidx[tid];
        if (idx >= nCells) idx = nCells - 1;          // defensive clamp
        const float* yc = ybase + (long long)idx * 85;
        float gx = yc[1], gy = yc[2], gww = yc[3], ghh = yc[4];
        sxmin[tid] = gx - gww * 0.5f; sxmax[tid] = gx + gww * 0.5f;
        symin[tid] = gy - ghh * 0.5f; symax[tid] = gy + ghh * 0.5f;
        sba[tid]   = gww * ghh;
    }
    __syncthreads();

    // ---- negative-conf loss for this chunk (branchless) ----
    int p_ = cc / 3, a = cc - p_ * 3;
    int gh = p_ / S, gw = p_ - gh * S;
    float aw = c_anc[l * 3 + a][0], ah = c_anc[l * 3 + a][1];
    float px = (sigm(v03.y) + (float)gw) * invS;
    float py = (sigm(v03.z) + (float)gh) * invS;
    float pw = __expf(v03.w) * aw * invS, ph = __expf(v4) * ah * invS;
    float pxmin = px - pw * 0.5f, pxmax = px + pw * 0.5f;
    float pymin = py - ph * 0.5f, pymax = py + ph * 0.5f;
    float parea = pw * ph;
    bool hit = false;
    // iou >= 0.5  <=>  2*inter >= pa+ba-inter  <=>  3*inter >= pa+ba
    for (int i = 0; i < MB; ++i) {
        float iw = fminf(pxmax, sxmax[i]) - fmaxf(pxmin, sxmin[i]);
        float ih = fminf(pymax, symax[i]) - fmaxf(pymin, symin[i]);
        float inter = fmaxf(iw, 0.f) * fmaxf(ih, 0.f);
        hit = hit || (3.f * inter >= parea + sba[i]);
    }
    bool posbit = (swords[cc >> 6] >> (cc & 63)) & 1ULL;
    float conf = sigm(v03.x);
    float bval = fmaxf(conf, 0.f) + __logf(1.f + __expf(-fabsf(conf)));
    float loss = (act && !posbit && !hit) ? bval : 0.f;

    // ---- positive losses (chunk 0 blocks only; block-uniform branch) ----
    if (blk == 0) {
        float wsum = 0.f;
        for (int i = wv; i < TC; i += 4) {
            int idx = sidx[i];
            if (idx >= nCells) idx = nCells - 1;      // defensive clamp
            const float* yc = ybase + (long long)idx * 85;
            const float* pp = pbase + (long long)idx * 85;
            float part = bce_f(yc[5 + lane], sigm(pp[5 + lane]));
            if (lane < 16)
                part += bce_f(yc[69 + lane], sigm(pp[69 + lane]));
            if (lane == 0) {
                int q = idx / 3, aa = idx - q * 3;
                int qh = q / S, qw = q - qh * S;
                float aw2 = c_anc[l * 3 + aa][0], ah2 = c_anc[l * 3 + aa][1];
                float t1 = yc[1], t2 = yc[2], t3 = yc[3], t4 = yc[4];
                float u0 = pp[0], u1 = pp[1], u2 = pp[2], u3 = pp[3], u4 = pp[4];
                part += bce_f(1.f, sigm(u0));
                float sc = 2.f - t3 * t4;
                float qx = (sigm(u1) + (float)qw) * invS;
                float qy = (sigm(u2) + (float)qh) * invS;
                part += sc * (bce_f(t1 * Sf - (float)qw, qx) +
                              bce_f(t2 * Sf - (float)qh, qy));
                float qpw = __expf(u3) * aw2 * invS;
                float qph = __expf(u4) * ah2 * invS;
                float twx = __logf(t3 / aw2 * 416.f);
                float twy = __logf(t4 / ah2 * 416.f);
                part += sc * 0.5f *
                        ((twx - qpw) * (twx - qpw) + (twy - qph) * (twy - qph));
            }
#pragma unroll
            for (int off = 32; off > 0; off >>= 1)
                part += __shfl_down(part, off, 64);
            if (lane == 0) wsum += part;
        }
        if (lane == 0) loss += wsum;
    }

    // block reduction -> one atomicAdd per block
#pragma unroll
    for (int off = 32; off > 0; off >>= 1)
        loss += __shfl_down(loss, off, 64);
    __shared__ float wred[4];
    if (lane == 0) wred[wv] = loss;
    __syncthreads();
    if (tid == 0)
        atomicAdd(out + b, wred[0] + wred[1] + wred[2] + wred[3]);
}

extern "C" void kernel_launch(void* const* d_in, const int* in_sizes, int n_in,
                              void* d_out, int out_size, void* d_ws, size_t ws_size,
                              hipStream_t stream) {
    (void)in_sizes; (void)n_in; (void)out_size; (void)d_ws; (void)ws_size;
    const float* yt  = (const float*)d_in[0];
    const float* p13 = (const float*)d_in[1];
    const float* p26 = (const float*)d_in[2];
    const float* p52 = (const float*)d_in[3];
    float* out = (float*)d_out;

    init_k<<<1, 32, 0, stream>>>(out);
    loss_k<<<32 * 42, 256, 0, stream>>>(yt, p13, p26, p52, out);
}

// Round 6
// 236.127 us; speedup vs baseline: 1.1231x; 1.1231x over previous
//
#include <hip/hip_runtime.h>

#define MAXB 64
#define CAP 256
#define BLK_PER_BATCH 6

__constant__ float c_anc[9][2] = {
    {116.f, 90.f}, {156.f, 198.f}, {373.f, 326.f},
    { 30.f, 61.f}, { 62.f, 45.f}, { 59.f, 119.f},
    { 10.f, 13.f}, { 16.f, 30.f}, { 33.f, 23.f}};

typedef float floatx4 __attribute__((ext_vector_type(4), aligned(4)));

// fast transcendentals (v_exp/v_log/v_rcp); ~1e-6 rel per term, output ~1.7e4
// with threshold 345.6 -> ample margin.
__device__ __forceinline__ float sigm(float x) {
    return __builtin_amdgcn_rcpf(1.f + __expf(-x));
}
// bce_logits(t,x) = max(x,0) - x*t + log1p(exp(-|x|))
__device__ __forceinline__ float bce_f(float t, float x) {
    return fmaxf(x, 0.f) - x * t + __logf(1.f + __expf(-fabsf(x)));
}

__global__ void init_k(float* __restrict__ out) { out[threadIdx.x] = 0.f; }

// 16-wave obj scan: wave wv covers words wv, wv+16, ... of the pair's bitmap.
template <int ITERS>
__device__ __forceinline__ void scan_obj(const float* __restrict__ ybase,
                                         int nCells, int nwords, int lane,
                                         int wv, unsigned long long* swords) {
    float ov[ITERS];
#pragma unroll
    for (int k = 0; k < ITERS; ++k) {
        int wi = k * 16 + wv;
        int c = (wi << 6) + lane;
        ov[k] = (wi < nwords && c < nCells) ? ybase[(long long)c * 85] : 0.f;
    }
#pragma unroll
    for (int k = 0; k < ITERS; ++k) {
        int wi = k * 16 + wv;
        unsigned long long m = __ballot(ov[k] > 0.5f);
        if (lane == 0 && wi < nwords) swords[wi] = m;
    }
}

// 192 blocks x 1024 threads. Per batch: j=0 -> 13x13 (507 cells),
// j=1 -> 26x26 (2028), j=2..5 -> 52x52 chunk j-2 (2028 each).
// Each block is fully self-contained: it re-derives its pair's positive set
// from y_true in LDS (no workspace -> nothing for the 0xAA poison to corrupt).
__global__ __launch_bounds__(1024) void loss_k(
    const float* __restrict__ yt,
    const float* __restrict__ p13, const float* __restrict__ p26,
    const float* __restrict__ p52, float* __restrict__ out)
{
    int bid = blockIdx.x, tid = threadIdx.x;
    int b = bid / BLK_PER_BATCH, j = bid - b * BLK_PER_BATCH;
    int l, blk, S, n0, nwords, start, cnt;
    if (j == 0)      { l = 0; blk = 0;     S = 13; n0 = 0;   nwords = 8;   start = 0;              cnt = 507;  }
    else if (j == 1) { l = 1; blk = 0;     S = 26; n0 = 169; nwords = 32;  start = 0;              cnt = 2028; }
    else             { l = 2; blk = j - 2; S = 52; n0 = 845; nwords = 128; start = (j - 2) * 2028; cnt = 2028; }
    int nCells = S * S * 3;
    float Sf = (float)S;
    float invS = __builtin_amdgcn_rcpf(Sf);
    const float* ybase = yt + (long long)(b * 3549 + n0) * 255;
    const float* pred  = (l == 0) ? p13 : (l == 1) ? p26 : p52;
    const float* pbase = pred + (long long)b * S * S * 255;
    int lane = tid & 63, wv = tid >> 6;

    // ---- issue this block's negative-cell pred loads up-front (<=2 cells) --
    int c0 = start + tid;
    int c1 = start + tid + 1024;
    bool act0 = (tid < cnt) && (c0 < nCells);
    bool act1 = (tid + 1024 < cnt) && (c1 < nCells);
    int cc0 = act0 ? c0 : 0, cc1 = act1 ? c1 : 0;
    const float* pp0 = pbase + (long long)cc0 * 85;
    const float* pp1 = pbase + (long long)cc1 * 85;
    floatx4 v03_0 = *(const floatx4*)pp0;
    float v4_0 = pp0[4];
    floatx4 v03_1 = *(const floatx4*)pp1;
    float v4_1 = pp1[4];

    __shared__ unsigned long long swords[128];
    __shared__ int sidx[CAP];
    __shared__ int sbase2[2];
    __shared__ int stot_s;
    __shared__ float sxmin[MAXB], sxmax[MAXB], symin[MAXB], symax[MAXB], sba[MAXB];

    // ---- obj scan of the whole pair column (overlaps the loads above) ------
    if (l == 0)      scan_obj<1>(ybase, nCells, nwords, lane, wv, swords);
    else if (l == 1) scan_obj<2>(ybase, nCells, nwords, lane, wv, swords);
    else             scan_obj<8>(ybase, nCells, nwords, lane, wv, swords);
    __syncthreads();

    // ---- exclusive prefix over word popcounts (waves 0/1, shfl scan) -------
    unsigned long long w = 0ULL;
    int pc = 0;
    if (tid < 128) { w = (tid < nwords) ? swords[tid] : 0ULL; pc = __popcll(w); }
    int x = pc;
#pragma unroll
    for (int d = 1; d < 64; d <<= 1) {
        int y = __shfl_up(x, d, 64);
        if (lane >= d) x += y;
    }
    if (tid < 128 && lane == 63) sbase2[wv] = x;
    __syncthreads();
    if (tid == 0) stot_s = sbase2[0] + sbase2[1];
    if (tid < 128) {
        int base = x - pc + (wv ? sbase2[0] : 0);
        unsigned long long ww = w;
        while (ww) {
            int bit = __ffsll((long long)ww) - 1;
            if (base < CAP) sidx[base] = tid * 64 + bit;
            ++base;
            ww &= ww - 1;
        }
    }
    __syncthreads();

    int stot = stot_s;
    int TC = stot < CAP ? stot : CAP;
    int MB = TC < MAXB ? TC : MAXB;   // == top_k(64) box set (index-ordered)
    if (tid < MB) {
        int idx = sidx[tid];
        if (idx >= nCells) idx = nCells - 1;          // defensive clamp
        const float* yc = ybase + (long long)idx * 85;
        float gx = yc[1], gy = yc[2], gww = yc[3], ghh = yc[4];
        sxmin[tid] = gx - gww * 0.5f; sxmax[tid] = gx + gww * 0.5f;
        symin[tid] = gy - ghh * 0.5f; symax[tid] = gy + ghh * 0.5f;
        sba[tid]   = gww * ghh;
    }
    __syncthreads();

    // ---- negative-conf losses for this block's <=2028 cells (branchless) ---
    float loss = 0.f;
#pragma unroll
    for (int it = 0; it < 2; ++it) {
        int cc = it ? cc1 : cc0;
        bool act = it ? act1 : act0;
        floatx4 v03 = it ? v03_1 : v03_0;
        float v4 = it ? v4_1 : v4_0;

        int p_ = cc / 3, a = cc - p_ * 3;
        int gh = p_ / S, gw = p_ - gh * S;
        float aw = c_anc[l * 3 + a][0], ah = c_anc[l * 3 + a][1];
        float px = (sigm(v03.y) + (float)gw) * invS;
        float py = (sigm(v03.z) + (float)gh) * invS;
        float pw = __expf(v03.w) * aw * invS, ph = __expf(v4) * ah * invS;
        float pxmin = px - pw * 0.5f, pxmax = px + pw * 0.5f;
        float pymin = py - ph * 0.5f, pymax = py + ph * 0.5f;
        float parea = pw * ph;
        bool hit = false;
        // iou >= 0.5  <=>  2*inter >= pa+ba-inter  <=>  3*inter >= pa+ba
        for (int i = 0; i < MB; ++i) {
            float iw = fminf(pxmax, sxmax[i]) - fmaxf(pxmin, sxmin[i]);
            float ih = fminf(pymax, symax[i]) - fmaxf(pymin, symin[i]);
            float inter = fmaxf(iw, 0.f) * fmaxf(ih, 0.f);
            hit = hit || (3.f * inter >= parea + sba[i]);
        }
        bool posbit = (swords[cc >> 6] >> (cc & 63)) & 1ULL;
        float conf = sigm(v03.x);
        float bval = fmaxf(conf, 0.f) + __logf(1.f + __expf(-fabsf(conf)));
        loss += (act && !posbit && !hit) ? bval : 0.f;
    }

    // ---- positive losses (blk 0 of each pair; block-uniform branch) --------
    if (blk == 0) {
        float wsum = 0.f;
        for (int i = wv; i < TC; i += 16) {
            int idx = sidx[i];
            if (idx >= nCells) idx = nCells - 1;      // defensive clamp
            const float* yc = ybase + (long long)idx * 85;
            const float* pp = pbase + (long long)idx * 85;
            float part = bce_f(yc[5 + lane], sigm(pp[5 + lane]));
            if (lane < 16)
                part += bce_f(yc[69 + lane], sigm(pp[69 + lane]));
            if (lane == 0) {
                int q = idx / 3, aa = idx - q * 3;
                int qh = q / S, qw = q - qh * S;
                float aw2 = c_anc[l * 3 + aa][0], ah2 = c_anc[l * 3 + aa][1];
                float t1 = yc[1], t2 = yc[2], t3 = yc[3], t4 = yc[4];
                float u0 = pp[0], u1 = pp[1], u2 = pp[2], u3 = pp[3], u4 = pp[4];
                part += bce_f(1.f, sigm(u0));
                float sc = 2.f - t3 * t4;
                float qx = (sigm(u1) + (float)qw) * invS;
                float qy = (sigm(u2) + (float)qh) * invS;
                part += sc * (bce_f(t1 * Sf - (float)qw, qx) +
                              bce_f(t2 * Sf - (float)qh, qy));
                float qpw = __expf(u3) * aw2 * invS;
                float qph = __expf(u4) * ah2 * invS;
                float twx = __logf(t3 / aw2 * 416.f);
                float twy = __logf(t4 / ah2 * 416.f);
                part += sc * 0.5f *
                        ((twx - qpw) * (twx - qpw) + (twy - qph) * (twy - qph));
            }
#pragma unroll
            for (int off = 32; off > 0; off >>= 1)
                part += __shfl_down(part, off, 64);
            if (lane == 0) wsum += part;
        }
        if (lane == 0) loss += wsum;
    }

    // ---- block reduction -> one atomicAdd per block -------------------------
#pragma unroll
    for (int off = 32; off > 0; off >>= 1)
        loss += __shfl_down(loss, off, 64);
    __shared__ float wred[16];
    if (lane == 0) wred[wv] = loss;
    __syncthreads();
    if (tid == 0) {
        float s = 0.f;
#pragma unroll
        for (int k = 0; k < 16; ++k) s += wred[k];
        atomicAdd(out + b, s);
    }
}

extern "C" void kernel_launch(void* const* d_in, const int* in_sizes, int n_in,
                              void* d_out, int out_size, void* d_ws, size_t ws_size,
                              hipStream_t stream) {
    (void)in_sizes; (void)n_in; (void)out_size; (void)d_ws; (void)ws_size;
    const float* yt  = (const float*)d_in[0];
    const float* p13 = (const float*)d_in[1];
    const float* p26 = (const float*)d_in[2];
    const float* p52 = (const float*)d_in[3];
    float* out = (float*)d_out;

    init_k<<<1, 32, 0, stream>>>(out);
    loss_k<<<32 * BLK_PER_BATCH, 1024, 0, stream>>>(yt, p13, p26, p52, out);
}